// Round 3
// baseline (508.631 us; speedup 1.0000x reference)
//
#include <hip/hip_runtime.h>
#include <math.h>

// CoAttentionLayer fp16-MFMA pipeline, round 5: barrier-free rel K-loop +
// XCD-locality swizzle in the side kernel. B=128, L=512, D=256, A=64.
//
// Pipeline:
//  cvt:   Q,K -> fp16; w_rel^T, W_q^T, W_k^T -> fp16 (transposed, K-major)
//  proj:  qp = Qh@Wq, kp = Kh@Wk  (fp16 row-major + per-batch transposed)
//  qw:    qw = Qh@w_rel for ALL batches            [B*512, 256] fp16
//  side (sideK=0, Q): per (64-q-row tile, b):
//     A = qw tile (64x256) RESIDENT in LDS (loaded once);
//     loop n0=0..3: rel subtile = A @ Kh[n0]^T with B fragments loaded
//       DIRECT global->reg (no LDS staging, no barriers in K-loop);
//       tanh -> LDS tile; pacc += tile @ kpT-frags (in-reg across n0);
//     epilogue: qlog[q] = sum_a tanh(qp+pacc)*W_qa  (shfl reduce)
//  side (sideK=1, K): same code on A=Kh (rel^T = Kh@qw^T), -> klog.
//  softmax over seq -> att weights (d_out tail region)
//  weighted outputs = att_w * inputs (overwrites scratch region LAST)
//
// vs round 4:
//  - rel K-loop: B direct-to-reg; 2 barriers/n0 (tile exchange) vs 10.
//  - grid 2048 1D with pair-major XCD swizzle: the 8 tt-blocks sharing one
//    (b,side) B-stream land on the SAME XCD consecutively -> B fetched from
//    HBM once per pair (~12 concurrent pairs x 256KB = 3MB < 4MB L2/XCD).
//
// ws layout (shorts): Qh 16.78M | Kh 16.78M | qp 4.19M | kp 4.19M | qlog/klog f32
// d_out scratch (till weight_kernel; att region starts at byte 134,217,728):
//   qw [0, 33,554,432) | qpT [100,663,296,...) | kpT [109,051,904,...)
//   wrelT [117,440,512) | WqT [117,571,584) | WkT [117,604,352)

#define SEQ 512
#define DIM 256
#define ADIM 64
#define OUT_QATT ((size_t)33554432)  // float offset of q_att_w in d_out

using hfrag = __attribute__((ext_vector_type(8))) _Float16;
using s4 = __attribute__((ext_vector_type(4))) short;
using f4 = __attribute__((ext_vector_type(4))) float;
typedef unsigned int u32;

__device__ __forceinline__ void gl_lds16(const short* g, short* l) {
  __builtin_amdgcn_global_load_lds((const __attribute__((address_space(1))) u32*)g,
                                   (__attribute__((address_space(3))) u32*)l, 16, 0, 0);
}

__device__ __forceinline__ short f2h(float x) {  // fp32 -> fp16 RNE bit pattern
  _Float16 h = (_Float16)x;
  return __builtin_bit_cast(short, h);
}
__device__ __forceinline__ float h2f(short s) {
  return (float)__builtin_bit_cast(_Float16, s);
}
__device__ __forceinline__ float tanhf_fast(float x) {
  float e = __expf(2.0f * x);
  return 1.0f - 2.0f / (e + 1.0f);
}

// ---------------- MFMA core (for proj/qw): C = A @ Bt^T ----------------
// A: [>=tileM, KTOT] K-major fp16, pre-offset. Bt: [>=tileN, KTOT] K-major.
// LDS cols XOR-swizzled by row&7.  256 threads = 4 waves.

template <int KTOT>
__device__ __forceinline__ void core128(const short* __restrict__ A,
                                        const short* __restrict__ Bt,
                                        short* sA, short* sB, f4 acc[4][4]) {
  const int t = threadIdx.x;
  const int lane = t & 63, wave = t >> 6;
  const int wm = (wave & 1) << 6, wn = (wave >> 1) << 6;
  const int l15 = lane & 15, qd = lane >> 4;
  const int srow = t >> 3, scol = (t & 7) << 3;
  for (int k0 = 0; k0 < KTOT; k0 += 64) {
#pragma unroll
    for (int i = 0; i < 4; i++) {
      const int row = srow + (i << 5);
      const int gcol = k0 + (scol ^ ((row & 7) << 3));
      gl_lds16(&A[(size_t)row * KTOT + gcol], &sA[t * 8 + i * 2048]);
      gl_lds16(&Bt[(size_t)row * KTOT + gcol], &sB[t * 8 + i * 2048]);
    }
    __syncthreads();
#pragma unroll
    for (int ks = 0; ks < 2; ks++) {
      hfrag af[4], bg[4];
      const int kk = (ks << 5) + (qd << 3);
#pragma unroll
      for (int i = 0; i < 4; i++) {
        const int ar = wm + (i << 4) + l15;
        const int br = wn + (i << 4) + l15;
        af[i] = *(const hfrag*)&sA[(ar << 6) + (kk ^ ((ar & 7) << 3))];
        bg[i] = *(const hfrag*)&sB[(br << 6) + (kk ^ ((br & 7) << 3))];
      }
#pragma unroll
      for (int i = 0; i < 4; i++)
#pragma unroll
        for (int j = 0; j < 4; j++)
          acc[i][j] = __builtin_amdgcn_mfma_f32_16x16x32_f16(af[i], bg[j], acc[i][j], 0, 0, 0);
    }
    __syncthreads();
  }
}

template <int KTOT>
__device__ __forceinline__ void core64(const short* __restrict__ A,
                                       const short* __restrict__ Bt,
                                       short* sA, short* sB, f4 acc[4][2]) {
  const int t = threadIdx.x;
  const int lane = t & 63, wave = t >> 6;
  const int wm = (wave & 1) << 6, wn = (wave >> 1) << 5;
  const int l15 = lane & 15, qd = lane >> 4;
  const int srow = t >> 3, scol = (t & 7) << 3;
  for (int k0 = 0; k0 < KTOT; k0 += 64) {
#pragma unroll
    for (int i = 0; i < 4; i++) {
      const int row = srow + (i << 5);
      const int gcol = k0 + (scol ^ ((row & 7) << 3));
      gl_lds16(&A[(size_t)row * KTOT + gcol], &sA[t * 8 + i * 2048]);
      if (i < 2) gl_lds16(&Bt[(size_t)row * KTOT + gcol], &sB[t * 8 + i * 2048]);
    }
    __syncthreads();
#pragma unroll
    for (int ks = 0; ks < 2; ks++) {
      hfrag af[4], bg[2];
      const int kk = (ks << 5) + (qd << 3);
#pragma unroll
      for (int i = 0; i < 4; i++) {
        const int ar = wm + (i << 4) + l15;
        af[i] = *(const hfrag*)&sA[(ar << 6) + (kk ^ ((ar & 7) << 3))];
      }
#pragma unroll
      for (int j = 0; j < 2; j++) {
        const int br = wn + (j << 4) + l15;
        bg[j] = *(const hfrag*)&sB[(br << 6) + (kk ^ ((br & 7) << 3))];
      }
#pragma unroll
      for (int i = 0; i < 4; i++)
#pragma unroll
        for (int j = 0; j < 2; j++)
          acc[i][j] = __builtin_amdgcn_mfma_f32_16x16x32_f16(af[i], bg[j], acc[i][j], 0, 0, 0);
    }
    __syncthreads();
  }
}

// ---------------- kernels ----------------

// inputs -> fp16; small weights transposed+converted
__global__ __launch_bounds__(256) void cvt_kernel(const float* __restrict__ Q,
                                                  const float* __restrict__ K,
                                                  const float* __restrict__ wrel,
                                                  const float* __restrict__ Wq,
                                                  const float* __restrict__ Wk,
                                                  short* __restrict__ Qh, short* __restrict__ Kh,
                                                  short* __restrict__ wrelT,
                                                  short* __restrict__ WqT,
                                                  short* __restrict__ WkT) {
  const int bid = blockIdx.x;
  if (bid < 32768) {
    const size_t g = ((size_t)bid << 8) + threadIdx.x;  // float4 idx, 8,388,608 total
    const int side = (int)(g >> 22);
    const size_t loc = g & 4194303;
    const float4 v = ((const float4*)(side ? K : Q))[loc];
    s4 o;
    o[0] = f2h(v.x); o[1] = f2h(v.y); o[2] = f2h(v.z); o[3] = f2h(v.w);
    *(s4*)&(side ? Kh : Qh)[loc << 2] = o;
  } else {
    const int b2 = bid - 32768;
    if (b2 < 64) {  // wrelT[e*256+d] = wrel[d*256+e], 65536 elems
      const int i = (b2 << 8) + threadIdx.x;
#pragma unroll
      for (int u = 0; u < 4; u++) {
        const int idx = (i << 2) + u;
        const int e = idx >> 8, d = idx & 255;
        wrelT[idx] = f2h(wrel[(d << 8) + e]);
      }
    } else if (b2 < 72) {  // WqT[a*256+d] = Wq[d*64+a], 16384 elems
      const int i = ((b2 - 64) << 8) + threadIdx.x;
#pragma unroll
      for (int u = 0; u < 8; u++) {
        const int idx = (i << 3) + u;
        const int a = idx >> 8, d = idx & 255;
        WqT[idx] = f2h(Wq[(d << 6) + a]);
      }
    } else if (b2 < 80) {
      const int i = ((b2 - 72) << 8) + threadIdx.x;
#pragma unroll
      for (int u = 0; u < 8; u++) {
        const int idx = (i << 3) + u;
        const int a = idx >> 8, d = idx & 255;
        WkT[idx] = f2h(Wk[(d << 6) + a]);
      }
    }
  }
}

// qp/kp = X @ W  (tile 128x64, K=256); writes row-major + per-batch transposed
__global__ __launch_bounds__(256) void proj_kernel(const short* __restrict__ Qh,
                                                   const short* __restrict__ Kh,
                                                   const short* __restrict__ WqT,
                                                   const short* __restrict__ WkT,
                                                   short* __restrict__ qp, short* __restrict__ kp,
                                                   short* __restrict__ qpT, short* __restrict__ kpT) {
  __shared__ short sA[8192];
  __shared__ short sB[4096];
  const int which = blockIdx.y;
  const short* A = which ? Kh : Qh;
  const short* Bt = which ? WkT : WqT;
  short* P = which ? kp : qp;
  short* PT = which ? kpT : qpT;
  const int m0 = blockIdx.x << 7;
  f4 acc[4][2];
  const f4 fz = {0.f, 0.f, 0.f, 0.f};
#pragma unroll
  for (int i = 0; i < 4; i++)
#pragma unroll
    for (int j = 0; j < 2; j++) acc[i][j] = fz;
  core64<256>(A + (size_t)m0 * 256, Bt, sA, sB, acc);
  const int lane = threadIdx.x & 63, wave = threadIdx.x >> 6;
  const int wm = (wave & 1) << 6, wn = (wave >> 1) << 5;
  const int l15 = lane & 15, qd = lane >> 4;
#pragma unroll
  for (int i = 0; i < 4; i++)
#pragma unroll
    for (int j = 0; j < 2; j++) {
      s4 pack;
      const int gm0 = m0 + wm + (i << 4) + (qd << 2);
      const int a = wn + (j << 4) + l15;
#pragma unroll
      for (int r = 0; r < 4; r++) {
        pack[r] = f2h(acc[i][j][r]);
        P[(size_t)(gm0 + r) * ADIM + a] = pack[r];
      }
      const int bb = gm0 >> 9, ql = gm0 & 511;
      *(s4*)&PT[((size_t)bb * ADIM + a) * SEQ + ql] = pack;
    }
}

// qw = Qh @ w_rel for ALL batches (tile 128x128, K=256)
__global__ __launch_bounds__(256) void qw_kernel(const short* __restrict__ Qh,
                                                 const short* __restrict__ WrT,
                                                 short* __restrict__ qw) {
  __shared__ short sA[8192];
  __shared__ short sB[8192];
  const int m0 = blockIdx.x << 7, n0 = blockIdx.y << 7;
  f4 acc[4][4];
  const f4 fz = {0.f, 0.f, 0.f, 0.f};
#pragma unroll
  for (int i = 0; i < 4; i++)
#pragma unroll
    for (int j = 0; j < 4; j++) acc[i][j] = fz;
  core128<256>(Qh + (size_t)m0 * 256, WrT + (size_t)n0 * 256, sA, sB, acc);
  const int lane = threadIdx.x & 63, wave = threadIdx.x >> 6;
  const int wm = (wave & 1) << 6, wn = (wave >> 1) << 6;
  const int l15 = lane & 15, qd = lane >> 4;
#pragma unroll
  for (int i = 0; i < 4; i++)
#pragma unroll
    for (int j = 0; j < 4; j++)
#pragma unroll
      for (int r = 0; r < 4; r++) {
        const int row = m0 + wm + (i << 4) + (qd << 2) + r;
        const int col = n0 + wn + (j << 4) + l15;
        qw[(size_t)row * 256 + col] = f2h(acc[i][j][r]);
      }
}

// Symmetric side kernel. 1D grid 2048, 256 thr.
// Decode: pair = ((i>>6)<<3)|(i&7)  (0..255: b*2+side), tt = (i>>3)&7.
//   -> all 8 tt-blocks of a pair share i%8 (same XCD) and are consecutive
//      in per-XCD order -> B-stream L2-resident.
// sideK=0 (Q): Ares=qw,  Bstream=Kh, pT=kpT, prow=qp, W=W_qa -> qlog
// sideK=1 (K): Ares=Kh,  Bstream=qw, pT=qpT, prow=kp, W=W_ka -> klog
// A 64x256 resident LDS; per n0: rel subtile 64x128 (B direct global->reg,
// NO barriers), tanh->LDS tile, pacc += tile @ pT-frags (in-reg over n0);
// epilogue: logit = (tanh(prow + pacc) @ W) via shfl reduce.
// LDS 48KB; VGPR<=128 -> 3 blocks/CU.
__global__ __launch_bounds__(256, 4) void side_kernel(const short* __restrict__ qw,
                                                      const short* __restrict__ Kh,
                                                      const short* __restrict__ qpT,
                                                      const short* __restrict__ kpT,
                                                      const short* __restrict__ qp,
                                                      const short* __restrict__ kp,
                                                      const float* __restrict__ Wqa,
                                                      const float* __restrict__ Wka,
                                                      float* __restrict__ qlog,
                                                      float* __restrict__ klog) {
  __shared__ short sA[16384];  // 64 rows x 256, swizzled (resident)
  __shared__ short sT[8192];   // tanh tile 64x128, swizzled
  const int i = blockIdx.x;
  const int pair = ((i >> 6) << 3) | (i & 7);
  const int tt = (i >> 3) & 7;
  const int b = pair >> 1;
  const int sideK = pair & 1;

  const short* Asrc = sideK ? Kh : qw;
  const short* Bsrc = sideK ? qw : Kh;
  const short* pT = sideK ? qpT : kpT;
  const short* prow = sideK ? kp : qp;
  const float* Watt = sideK ? Wka : Wqa;
  float* logit = sideK ? klog : qlog;

  const int t = threadIdx.x;
  const int lane = t & 63, wave = t >> 6;
  const int l15 = lane & 15, qd = lane >> 4;
  const int wm = (wave & 1) << 5, wn = (wave >> 1) << 6;
  const f4 fz = {0.f, 0.f, 0.f, 0.f};

  // --- load A resident (64x256), pre-swizzled global cols, linear LDS dest ---
  {
    const short* Ag = Asrc + ((size_t)b * SEQ + tt * 64) * DIM;
    const int chunk = t & 31;  // 16B chunk within a row
    const int rb = t >> 5;     // 0..7
#pragma unroll
    for (int u = 0; u < 8; u++) {
      const int row = (u << 3) + rb;
      const int gcol = (chunk << 3) ^ ((row & 7) << 3);
      gl_lds16(&Ag[(size_t)row * DIM + gcol], &sA[(row << 8) + (chunk << 3)]);
    }
  }
  __syncthreads();

  f4 pacc[4];  // wave owns 16 q-rows x 64 a
#pragma unroll
  for (int j = 0; j < 4; j++) pacc[j] = fz;

  const short* pT_b = pT + (size_t)b * ADIM * SEQ;

  for (int n0 = 0; n0 < 4; n0++) {
    // --- rel subtile = Ares(64x256) @ B[n0](128x256)^T, B direct to regs ---
    f4 acc[2][4];
#pragma unroll
    for (int i2 = 0; i2 < 2; i2++)
#pragma unroll
      for (int j = 0; j < 4; j++) acc[i2][j] = fz;
    const short* Bg = Bsrc + ((size_t)b * SEQ + n0 * 128) * DIM;
#pragma unroll
    for (int k0 = 0; k0 < 256; k0 += 64) {
#pragma unroll
      for (int ks = 0; ks < 2; ks++) {
        const int kkA = k0 + (ks << 5) + (qd << 3);
        hfrag af[2], bg[4];
#pragma unroll
        for (int i2 = 0; i2 < 2; i2++) {
          const int ar = wm + (i2 << 4) + l15;
          af[i2] = *(const hfrag*)&sA[(ar << 8) + (kkA ^ ((ar & 7) << 3))];
        }
#pragma unroll
        for (int j = 0; j < 4; j++) {
          const int br = wn + (j << 4) + l15;
          bg[j] = *(const hfrag*)&Bg[(size_t)br * DIM + kkA];
        }
#pragma unroll
        for (int i2 = 0; i2 < 2; i2++)
#pragma unroll
          for (int j = 0; j < 4; j++)
            acc[i2][j] = __builtin_amdgcn_mfma_f32_16x16x32_f16(af[i2], bg[j], acc[i2][j], 0, 0, 0);
      }
    }
    // --- tanh -> fp16 tile (64x128) into sT ---
    __syncthreads();  // prev n0's pacc reads of sT complete
#pragma unroll
    for (int i2 = 0; i2 < 2; i2++)
#pragma unroll
      for (int j = 0; j < 4; j++) {
        const int row0 = wm + (i2 << 4) + (qd << 2);
        const int col = wn + (j << 4) + l15;
#pragma unroll
        for (int r = 0; r < 4; r++) {
          const int row = row0 + r;
          sT[(row << 7) + (col ^ ((row & 7) << 3))] = f2h(tanhf_fast(acc[i2][j][r]));
        }
      }
    __syncthreads();
    // --- pacc += tile @ pT-frags  (K = this n0's 128) ---
#pragma unroll
    for (int ks = 0; ks < 4; ks++) {
      const int kkk = (ks << 5) + (qd << 3);
      const int ar = (wave << 4) + l15;
      const hfrag aq = *(const hfrag*)&sT[(ar << 7) + (kkk ^ ((ar & 7) << 3))];
#pragma unroll
      for (int j2 = 0; j2 < 4; j2++) {
        const int a = (j2 << 4) + l15;
        const hfrag bq = *(const hfrag*)&pT_b[(size_t)a * SEQ + (n0 << 7) + kkk];
        pacc[j2] = __builtin_amdgcn_mfma_f32_16x16x32_f16(aq, bq, pacc[j2], 0, 0, 0);
      }
    }
  }

  // --- epilogue: logit[row] = sum_a tanh(prow + pacc) * Watt[a] ---
  const int row_l = (wave << 4) + (qd << 2);
  const size_t g0 = (size_t)b * SEQ + tt * 64 + row_l;
  float p[4] = {0.f, 0.f, 0.f, 0.f};
#pragma unroll
  for (int r = 0; r < 4; r++)
#pragma unroll
    for (int j2 = 0; j2 < 4; j2++) {
      const int a = (j2 << 4) + l15;
      p[r] += tanhf_fast(h2f(prow[(g0 + r) * ADIM + a]) + pacc[j2][r]) * Watt[a];
    }
#pragma unroll
  for (int off = 8; off; off >>= 1)
#pragma unroll
    for (int r = 0; r < 4; r++) p[r] += __shfl_down(p[r], off, 16);
  if (l15 == 0) {
#pragma unroll
    for (int r = 0; r < 4; r++) logit[g0 + r] = p[r];
  }
}

// softmax over seq dim -> att weights in d_out tail
__global__ __launch_bounds__(256) void softmax_kernel(const float* __restrict__ qlog,
                                                      const float* __restrict__ klog,
                                                      float* __restrict__ out) {
  const int bx = blockIdx.x;  // 0..255
  const int side = bx >> 7;
  const int b = bx & 127;
  const float* lg = (side ? klog : qlog) + (size_t)b * SEQ;
  float* o = out + OUT_QATT + (size_t)side * (128 * SEQ) + (size_t)b * SEQ;
  const int t = threadIdx.x;
  float v0 = lg[t];
  float v1 = lg[t + 256];
  float m = fmaxf(v0, v1);
#pragma unroll
  for (int off = 32; off; off >>= 1) m = fmaxf(m, __shfl_xor(m, off));
  __shared__ float sm[4], ss[4];
  const int w = t >> 6, l = t & 63;
  if (l == 0) sm[w] = m;
  __syncthreads();
  m = fmaxf(fmaxf(sm[0], sm[1]), fmaxf(sm[2], sm[3]));
  float e0 = expf(v0 - m), e1 = expf(v1 - m);
  float s = e0 + e1;
#pragma unroll
  for (int off = 32; off; off >>= 1) s += __shfl_xor(s, off);
  if (l == 0) ss[w] = s;
  __syncthreads();
  s = ss[0] + ss[1] + ss[2] + ss[3];
  float inv = 1.0f / s;
  o[t] = e0 * inv;
  o[t + 256] = e1 * inv;
}

// weighted_* = att_w * inputs (runs LAST: overwrites the scratch region)
__global__ __launch_bounds__(256) void weight_kernel(const float* __restrict__ queries,
                                                     const float* __restrict__ keys,
                                                     float* __restrict__ out) {
  const size_t g = (size_t)blockIdx.x * 256 + threadIdx.x;  // float4 index
  const int side = (int)(g >> 22);
  const size_t loc = g & 4194303;
  const size_t row = loc >> 6;
  const float* aw = out + OUT_QATT + (size_t)side * (128 * SEQ);
  const float4* src = (const float4*)(side ? keys : queries);
  const float w = aw[row];
  float4 v = src[loc];
  float4 r = {v.x * w, v.y * w, v.z * w, v.w * w};
  ((float4*)out)[g] = r;
}

extern "C" void kernel_launch(void* const* d_in, const int* in_sizes, int n_in,
                              void* d_out, int out_size, void* d_ws, size_t ws_size,
                              hipStream_t stream) {
  const float* queries = (const float*)d_in[0];
  const float* keys = (const float*)d_in[1];
  const float* w_rel = (const float*)d_in[2];
  const float* W_q = (const float*)d_in[3];
  const float* W_k = (const float*)d_in[4];
  const float* W_qa = (const float*)d_in[5];
  const float* W_ka = (const float*)d_in[6];
  float* out = (float*)d_out;

  // ws layout (shorts / floats)
  short* Qh = (short*)d_ws;
  short* Kh = Qh + 16777216;
  short* qp = Kh + 16777216;
  short* kp = qp + 4194304;
  float* qlog = (float*)(kp + 4194304);
  float* klog = qlog + 65536;

  // d_out scratch (safe until weight_kernel; att region starts at 134,217,728)
  char* ob = (char*)d_out;
  short* qw_s = (short*)ob;                    // 33,554,432 B
  short* qpT = (short*)(ob + 100663296);       // 8,388,608 B
  short* kpT = (short*)(ob + 109051904);       // 8,388,608 B
  short* wrelT = (short*)(ob + 117440512);     // 131,072 B
  short* WqT = (short*)(ob + 117571584);       // 32,768 B
  short* WkT = (short*)(ob + 117604352);       // 32,768 B

  cvt_kernel<<<32848, 256, 0, stream>>>(queries, keys, w_rel, W_q, W_k, Qh, Kh, wrelT, WqT, WkT);
  proj_kernel<<<dim3(512, 2), 256, 0, stream>>>(Qh, Kh, WqT, WkT, qp, kp, qpT, kpT);
  qw_kernel<<<dim3(512, 2), 256, 0, stream>>>(Qh, wrelT, qw_s);
  side_kernel<<<2048, 256, 0, stream>>>(qw_s, Kh, qpT, kpT, qp, kp, W_qa, W_ka, qlog, klog);
  softmax_kernel<<<256, 256, 0, stream>>>(qlog, klog, out);
  weight_kernel<<<32768, 256, 0, stream>>>(queries, keys, out);
}